// Round 9
// baseline (135.507 us; speedup 1.0000x reference)
//
#include <hip/hip_runtime.h>

#define NT 16
#define NTILES 256
#define INV_TILE (1.0f/64.0f)
#define CHUNK 2048          // points per chunk (k_hist/k_scatter share chunking)
#define THREADS 1024
#define NWAVES 16
#define FSTRIDE 2049        // feature plane stride

typedef float fv4 __attribute__((ext_vector_type(4)));

__device__ __forceinline__ int tile_of(float x, float y) {
    int tx = (int)floorf(x * INV_TILE);
    tx = tx < 0 ? 0 : (tx > NT - 1 ? NT - 1 : tx);
    int ty = (int)floorf(y * INV_TILE);
    ty = ty < 0 ? 0 : (ty > NT - 1 ? NT - 1 : ty);
    return ty * NT + tx;
}

// 64-lane same-tile group mask via 8 ballots (tile id is 8 bits).
__device__ __forceinline__ unsigned long long match_mask(int t, bool valid) {
    unsigned long long m = ~0ull;
#pragma unroll
    for (int b = 0; b < 8; ++b) {
        unsigned long long bal = __ballot((t >> b) & 1);
        m &= ((t >> b) & 1) ? bal : ~bal;
    }
    m &= __ballot(valid);
    return m;
}

// K1: counts only -> one coalesced row gTot[b][t]. No atomics, no memset dep.
__global__ __launch_bounds__(THREADS, 8) void k_hist(const float2* __restrict__ pos2d,
                                                     int* __restrict__ gTot,
                                                     int N) {
    __shared__ unsigned short cnt[NWAVES][NTILES];  // 8 KB, per-wave private
    const int tid = threadIdx.x;
    const int wl = tid >> 6, lane = tid & 63;
    const int base_i = blockIdx.x * CHUNK;
    ((int*)cnt)[tid] = 0;                           // 2048 ints
    ((int*)cnt)[tid + THREADS] = 0;
    __syncthreads();
#pragma unroll
    for (int r = 0; r < 2; ++r) {
        int o = wl * 128 + r * 64 + lane;
        int i = base_i + o;
        bool valid = i < N;
        int t = 0;
        if (valid) { float2 p = pos2d[i]; t = tile_of(p.x, p.y); }
        unsigned long long m = match_mask(t, valid);
        if (valid) {
            unsigned long long below = m & ((1ull << lane) - 1ull);
            if (below == 0ull)                      // group leader adds group size
                cnt[wl][t] = (unsigned short)(cnt[wl][t] + __popcll(m));
        }
    }
    __syncthreads();
    if (tid < NTILES) {
        int tot = 0;
#pragma unroll
        for (int w = 0; w < NWAVES; ++w) tot += cnt[w][tid];
        gTot[(size_t)blockIdx.x * NTILES + tid] = tot;
    }
}

// K2: one block per tile t. Scan the tile's chunk-count column -> transposed
// within-tile bases gBaseT[t][chunk]. Also gcnt[t] + out_counts. NWA <= 2048.
__global__ __launch_bounds__(512) void k_scan(const int* __restrict__ gTot,
                                              int* __restrict__ gBaseT,
                                              int* __restrict__ gcnt,
                                              float* __restrict__ out_counts,
                                              int NWA) {
    const int t = blockIdx.x;
    const int tid = threadIdx.x;
    const int wl = tid >> 6, lane = tid & 63;
    __shared__ int wsum[8];

    int vals[4];
    const int base_row = tid * 4;
#pragma unroll
    for (int k = 0; k < 4; ++k) {
        int row = base_row + k;
        vals[k] = (row < NWA) ? gTot[(size_t)row * NTILES + t] : 0;
    }
    int tv = vals[0] + vals[1] + vals[2] + vals[3];
    int x = tv;
#pragma unroll
    for (int s = 1; s < 64; s <<= 1) {
        int y = __shfl_up(x, s);
        if (lane >= s) x += y;
    }
    if (lane == 63) wsum[wl] = x;
    __syncthreads();
    int wprefix = 0;
    for (int u = 0; u < wl; ++u) wprefix += wsum[u];
    int running = wprefix + (x - tv);               // exclusive within-tile base
#pragma unroll
    for (int k = 0; k < 4; ++k) {
        int row = base_row + k;
        if (row < NWA) gBaseT[(size_t)t * NWA + row] = running;
        running += vals[k];
    }
    if (tid == 0) {
        int total = 0;
#pragma unroll
        for (int u = 0; u < 8; ++u) total += wsum[u];
        gcnt[t] = total;
        out_counts[t] = (float)total;
    }
}

// PROCESS one chunk from pre-loaded registers. PREFETCH is spliced in after
// the A2 barrier, before phase-B stores (T14: next chunk's reads overlap
// this chunk's writes).
#define PROCESS(PP, CC, OO, cc, PREFETCH)                                    \
    {                                                                        \
        const int base_i = (cc) * CHUNK;                                     \
        ((int*)cnt)[tid] = 0;                                                \
        ((int*)cnt)[tid + THREADS] = 0;                                      \
        __syncthreads();   /* also separates prev phase-B reads from stage */\
        unsigned int meta[2];                                                \
        _Pragma("unroll")                                                    \
        for (int r2 = 0; r2 < 2; ++r2) {                                     \
            int o = wl * 128 + r2 * 64 + lane;                               \
            int i = base_i + o;                                              \
            bool valid = ((cc) < NWA) && (i < N);                            \
            int t = 0;                                                       \
            if (valid) {                                                     \
                float2 p = PP[r2]; fv4 cv = CC[r2]; float op = OO[r2];       \
                t = tile_of(p.x, p.y);                                       \
                float a = cv[0], bb2 = cv[1], d = cv[3];                     \
                float trace = a + d;                                         \
                float det = a * d - bb2 * bb2;   /* b == c (symmetric) */    \
                float term1 = 0.5f * trace;                                  \
                float term2 = 0.5f * sqrtf(fmaxf(trace * trace - 4.0f * det, 0.0f)); \
                float rad = fmaxf(term1 - term2, term1 + term2);             \
                float inv = 1.0f / det;                                      \
                sFeat[0 * FSTRIDE + o] = p.x;                                \
                sFeat[1 * FSTRIDE + o] = p.y;                                \
                sFeat[2 * FSTRIDE + o] = d * inv;                            \
                sFeat[3 * FSTRIDE + o] = -bb2 * inv;                         \
                sFeat[4 * FSTRIDE + o] = a * inv;                            \
                sFeat[5 * FSTRIDE + o] = op;                                 \
                sFeat[6 * FSTRIDE + o] = rad;                                \
            }                                                                \
            unsigned long long m = match_mask(t, valid);                     \
            unsigned int pk = 0x80000000u;                                   \
            if (valid) {                                                     \
                unsigned long long below = m & ((1ull << lane) - 1ull);      \
                int rank = __popcll(below);                                  \
                int b0 = cnt[wl][t];       /* lockstep read-before-write */  \
                if (below == 0ull) cnt[wl][t] = (unsigned short)(b0 + __popcll(m)); \
                pk = ((unsigned)t << 16) | (unsigned)(b0 + rank);            \
            }                                                                \
            meta[r2] = pk;                                                   \
        }                                                                    \
        __syncthreads();                                                     \
        int tot = 0, x2 = 0;                                                 \
        if (tid < NTILES) {                                                  \
            _Pragma("unroll")                                                \
            for (int w = 0; w < NWAVES; ++w) tot += cnt[w][tid];             \
            x2 = tot;                                                        \
            _Pragma("unroll")                                                \
            for (int s = 1; s < 64; s <<= 1) {                               \
                int y = __shfl_up(x2, s);                                    \
                if (lane >= s) x2 += y;                                      \
            }                                                                \
            if (lane == 63) wsum[wl] = x2;                                   \
        }                                                                    \
        __syncthreads();                                                     \
        if (tid < NTILES) {                                                  \
            int wpre = 0;                                                    \
            for (int u = 0; u < wl; ++u) wpre += wsum[u];                    \
            int run = wpre + x2 - tot;                                       \
            int gb = gbase[tid];                                             \
            int ob = gb - run;                                               \
            obase[tid] = ob;                                                 \
            base7[tid] = ob * 7;                                             \
            gbase[tid] = gb + tot;          /* advance for next chunk */     \
            _Pragma("unroll")                                                \
            for (int w = 0; w < NWAVES; ++w) {                               \
                int cw = cnt[w][tid];                                        \
                cnt[w][tid] = (unsigned short)run;                           \
                run += cw;                                                   \
            }                                                                \
        }                                                                    \
        __syncthreads();                                                     \
        _Pragma("unroll")                                                    \
        for (int r2 = 0; r2 < 2; ++r2) {                                     \
            unsigned int pk = meta[r2];                                      \
            if (!(pk & 0x80000000u)) {                                       \
                int o = wl * 128 + r2 * 64 + lane;                           \
                int t = pk >> 16;                                            \
                int pw = pk & 0xFFFF;                                        \
                slotPk[cnt[wl][t] + pw] = ((unsigned)t << 16) | (unsigned)o; \
            }                                                                \
        }                                                                    \
        __syncthreads();                                                     \
        PREFETCH                                                             \
        int nvalid = ((cc) < NWA) ? (N - base_i) : 0;                        \
        if (nvalid > CHUNK) nvalid = CHUNK;                                  \
        if (nvalid < 0) nvalid = 0;                                          \
        int nv7 = nvalid * 7;                                                \
        {                                                                    \
            int j = (int)((unsigned)tid / 7u);  /* j=f/7, c=f%7; 1024=146*7+2 */ \
            int c = tid - 7 * j;                                             \
            for (int f = tid; f < nv7; f += THREADS) {                       \
                unsigned int pk = slotPk[j];                                 \
                int t = pk >> 16;                                            \
                int o = pk & 0xFFFF;                                         \
                out_feat[(size_t)(base7[t] + f)] = sFeat[c * FSTRIDE + o];   \
                j += 146; c += 2;                                            \
                if (c >= 7) { c -= 7; j += 1; }                              \
            }                                                                \
        }                                                                    \
        for (int j2 = tid; j2 < nvalid; j2 += THREADS) {                     \
            unsigned int pk = slotPk[j2];                                    \
            out_order[obase[pk >> 16] + j2] = (float)(base_i + (int)(pk & 0xFFFF)); \
        }                                                                    \
    }

// K3: persistent PAIR-pipelined scatter. Each block owns chunks (2m, 2m+1):
// next chunk's global loads issue before this chunk's phase-B stores
// (read/write overlap), and the pair-internal segment-boundary lines are
// written back-to-back by the same CU (guaranteed L2 merge). XCD swizzle
// on pair index. LDS ~77 KB -> 2 blocks/CU x 16 waves = 32 waves/CU.
__global__ __launch_bounds__(THREADS, 8) void k_scatter(const float2* __restrict__ pos2d,
                                                        const float4* __restrict__ cov2d,
                                                        const float*  __restrict__ opacity,
                                                        const int*    __restrict__ gBaseT,
                                                        const int*    __restrict__ gcnt,
                                                        float* __restrict__ out_feat,
                                                        float* __restrict__ out_offsets,
                                                        float* __restrict__ out_order,
                                                        int N, int NWA) {
    __shared__ float sFeat[7 * FSTRIDE];            // 57.4 KB SoA feature planes
    __shared__ unsigned int slotPk[CHUNK];          // 8 KB: (t<<16)|o at sorted slot
    __shared__ unsigned short cnt[NWAVES][NTILES];  // 8 KB: per-wave counts -> bases
    __shared__ int gbase[NTILES];                   // running absolute base per tile
    __shared__ int base7[NTILES];
    __shared__ int obase[NTILES];
    __shared__ int wsum[NWAVES];

    const int tid = threadIdx.x;
    const int wl = tid >> 6, lane = tid & 63;
    const int b = blockIdx.x;

    // Bijective XCD swizzle (m204 form) on the PAIR index.
    const int nwg = gridDim.x;
    const int q = nwg >> 3, r = nwg & 7;
    const int xcd = b & 7, idx = b >> 3;
    const int pair = (xcd < r ? xcd * (q + 1) : r * (q + 1) + (xcd - r) * q) + idx;
    const int c0 = pair * 2;

    // ---- prefetch chunk c0 into registers ----
    float2 p0[2]; fv4 cv0[2]; float op0[2];
    float2 p1[2]; fv4 cv1[2]; float op1[2];
#pragma unroll
    for (int r2 = 0; r2 < 2; ++r2) {
        int i = c0 * CHUNK + wl * 128 + r2 * 64 + lane;
        if (i < N) {
            p0[r2]  = pos2d[i];
            cv0[r2] = __builtin_nontemporal_load((const fv4*)cov2d + i);
            op0[r2] = opacity[i];
        }
    }

    // ---- prologue: cross-tile offsets + pair's first-chunk bases ----
    {
        int ct = 0, x = 0, gbt = 0;
        if (tid < NTILES) {
            gbt = gBaseT[(size_t)tid * NWA + c0];   // within-tile base (chunk c0)
            ct = gcnt[tid];
            x = ct;
#pragma unroll
            for (int s = 1; s < 64; s <<= 1) {
                int y = __shfl_up(x, s);
                if (lane >= s) x += y;
            }
            if (lane == 63) wsum[wl] = x;
        }
        __syncthreads();
        if (tid < NTILES) {
            int wpre = 0;
            for (int u = 0; u < wl; ++u) wpre += wsum[u];
            int off = wpre + x - ct;                // sum over tiles < tid
            gbase[tid] = off + gbt;
            if (b == 0) out_offsets[tid] = (float)off;
        }
    }

    // ---- chunk c0 (prefetching c0+1 before its phase-B stores) ----
    PROCESS(p0, cv0, op0, c0,
        if (c0 + 1 < NWA) {
            for (int r3 = 0; r3 < 2; ++r3) {
                int i2 = (c0 + 1) * CHUNK + wl * 128 + r3 * 64 + lane;
                if (i2 < N) {
                    p1[r3]  = pos2d[i2];
                    cv1[r3] = __builtin_nontemporal_load((const fv4*)cov2d + i2);
                    op1[r3] = opacity[i2];
                }
            }
        }
    )
    // ---- chunk c0+1 ----
    PROCESS(p1, cv1, op1, c0 + 1, )
}

extern "C" void kernel_launch(void* const* d_in, const int* in_sizes, int n_in,
                              void* d_out, int out_size, void* d_ws, size_t ws_size,
                              hipStream_t stream) {
    const float2* pos2d   = (const float2*)d_in[0];
    const float4* cov2d   = (const float4*)d_in[1];
    const float*  opacity = (const float*)d_in[2];
    const int N = in_sizes[2];           // opacity element count

    float* out         = (float*)d_out;  // layout: feat | counts | offsets | order
    float* out_feat    = out;
    float* out_counts  = out + (size_t)N * 7;
    float* out_offsets = out_counts + NTILES;
    float* out_order   = out_offsets + NTILES;

    int nchunks = (N + CHUNK - 1) / CHUNK;   // 977 for N=2M (k_scan supports <=2048)
    int npairs  = (nchunks + 1) / 2;         // 489

    int* gTot   = (int*)d_ws;                          // [nchunks x NTILES]
    int* gBaseT = gTot + (size_t)nchunks * NTILES;     // [NTILES x nchunks]
    int* gcnt   = gBaseT + (size_t)NTILES * nchunks;   // [NTILES]

    k_hist<<<nchunks, THREADS, 0, stream>>>(pos2d, gTot, N);
    k_scan<<<NTILES, 512, 0, stream>>>(gTot, gBaseT, gcnt, out_counts, nchunks);
    k_scatter<<<npairs, THREADS, 0, stream>>>(pos2d, cov2d, opacity, gBaseT, gcnt,
                                              out_feat, out_offsets, out_order,
                                              N, nchunks);
}

// Round 10
// 131.869 us; speedup vs baseline: 1.0276x; 1.0276x over previous
//
#include <hip/hip_runtime.h>

#define NT 16
#define NTILES 256
#define INV_TILE (1.0f/64.0f)
#define CHUNK 2048          // points per chunk (k_hist/k_scatter share chunking)
#define THREADS 1024
#define NWAVES 16
#define FSTRIDE 2049        // feature plane stride

typedef float fv4 __attribute__((ext_vector_type(4)));

__device__ __forceinline__ int tile_of(float x, float y) {
    int tx = (int)floorf(x * INV_TILE);
    tx = tx < 0 ? 0 : (tx > NT - 1 ? NT - 1 : tx);
    int ty = (int)floorf(y * INV_TILE);
    ty = ty < 0 ? 0 : (ty > NT - 1 ? NT - 1 : ty);
    return ty * NT + tx;
}

// 64-lane same-tile group mask via 8 ballots (tile id is 8 bits).
__device__ __forceinline__ unsigned long long match_mask(int t, bool valid) {
    unsigned long long m = ~0ull;
#pragma unroll
    for (int b = 0; b < 8; ++b) {
        unsigned long long bal = __ballot((t >> b) & 1);
        m &= ((t >> b) & 1) ? bal : ~bal;
    }
    m &= __ballot(valid);
    return m;
}

// K1: counts only -> one coalesced row gTot[b][t]. No atomics, no memset dep.
__global__ __launch_bounds__(THREADS, 8) void k_hist(const float2* __restrict__ pos2d,
                                                     int* __restrict__ gTot,
                                                     int N) {
    __shared__ unsigned short cnt[NWAVES][NTILES];  // 8 KB, per-wave private
    const int tid = threadIdx.x;
    const int wl = tid >> 6, lane = tid & 63;
    const int base_i = blockIdx.x * CHUNK;
    ((int*)cnt)[tid] = 0;                           // 2048 ints
    ((int*)cnt)[tid + THREADS] = 0;
    __syncthreads();
#pragma unroll
    for (int r = 0; r < 2; ++r) {
        int o = wl * 128 + r * 64 + lane;
        int i = base_i + o;
        bool valid = i < N;
        int t = 0;
        if (valid) { float2 p = pos2d[i]; t = tile_of(p.x, p.y); }
        unsigned long long m = match_mask(t, valid);
        if (valid) {
            unsigned long long below = m & ((1ull << lane) - 1ull);
            if (below == 0ull)                      // group leader adds group size
                cnt[wl][t] = (unsigned short)(cnt[wl][t] + __popcll(m));
        }
    }
    __syncthreads();
    if (tid < NTILES) {
        int tot = 0;
#pragma unroll
        for (int w = 0; w < NWAVES; ++w) tot += cnt[w][tid];
        gTot[(size_t)blockIdx.x * NTILES + tid] = tot;
    }
}

// K2: one block per tile t. Scan the tile's chunk-count column (read-only
// sharing of gTot lines) -> TRANSPOSED within-tile bases gBaseT[t][chunk]
// (each output line written by exactly one block: no cross-XCD RMW).
// Also gcnt[t] + out_counts. NWA <= 2048.
__global__ __launch_bounds__(512) void k_scan(const int* __restrict__ gTot,
                                              int* __restrict__ gBaseT,
                                              int* __restrict__ gcnt,
                                              float* __restrict__ out_counts,
                                              int NWA) {
    const int t = blockIdx.x;
    const int tid = threadIdx.x;
    const int wl = tid >> 6, lane = tid & 63;
    __shared__ int wsum[8];

    int vals[4];
    const int base_row = tid * 4;
#pragma unroll
    for (int k = 0; k < 4; ++k) {
        int row = base_row + k;
        vals[k] = (row < NWA) ? gTot[(size_t)row * NTILES + t] : 0;
    }
    int tv = vals[0] + vals[1] + vals[2] + vals[3];
    int x = tv;
#pragma unroll
    for (int s = 1; s < 64; s <<= 1) {
        int y = __shfl_up(x, s);
        if (lane >= s) x += y;
    }
    if (lane == 63) wsum[wl] = x;
    __syncthreads();
    int wprefix = 0;
    for (int u = 0; u < wl; ++u) wprefix += wsum[u];
    int running = wprefix + (x - tv);               // exclusive within-tile base
#pragma unroll
    for (int k = 0; k < 4; ++k) {
        int row = base_row + k;
        if (row < NWA) gBaseT[(size_t)t * NWA + row] = running;
        running += vals[k];
    }
    if (tid == 0) {
        int total = 0;
#pragma unroll
        for (int u = 0; u < 8; ++u) total += wsum[u];
        gcnt[t] = total;
        out_counts[t] = (float)total;
    }
}

// K3: XCD-aware bijective chunk swizzle + NON-TEMPORAL cov2d load (cov is
// 32MB streamed exactly once; no-allocate keeps L2 free to hold pending
// partial write-lines at segment boundaries until the adjacent same-XCD
// chunk merges them), then the proven prologue + all-LDS stage / rank /
// permute / float-linear coalesced write-out.
// CHUNK=2048 @ 1024 threads: 2 blocks/CU x 16 waves = 32 waves/CU (cap).
__global__ __launch_bounds__(THREADS, 8) void k_scatter(const float2* __restrict__ pos2d,
                                                        const float4* __restrict__ cov2d,
                                                        const float*  __restrict__ opacity,
                                                        const int*    __restrict__ gBaseT,
                                                        const int*    __restrict__ gcnt,
                                                        float* __restrict__ out_feat,
                                                        float* __restrict__ out_offsets,
                                                        float* __restrict__ out_order,
                                                        int N, int NWA) {
    __shared__ float sFeat[7 * FSTRIDE];            // 57.4 KB SoA feature planes
    __shared__ unsigned int slotPk[CHUNK];          // 8 KB: (t<<16)|o at sorted slot
    __shared__ unsigned short cnt[NWAVES][NTILES];  // 8 KB: per-wave counts -> bases
    __shared__ int gbase[NTILES];                   // absolute dest base per tile
    __shared__ int base7[NTILES];
    __shared__ int obase[NTILES];
    __shared__ int wsum[NWAVES];

    const int tid = threadIdx.x;
    const int wl = tid >> 6, lane = tid & 63;
    const int b = blockIdx.x;

    // Bijective XCD swizzle (m204 form): dispatch round-robins blockIdx over
    // 8 XCDs; remap so XCD k owns a contiguous run of chunks.
    const int nwg = gridDim.x;
    const int q = nwg >> 3, r = nwg & 7;
    const int xcd = b & 7, idx = b >> 3;
    const int chunk = (xcd < r ? xcd * (q + 1) : r * (q + 1) + (xcd - r) * q) + idx;
    const int base_i = chunk * CHUNK;

    ((int*)cnt)[tid] = 0;
    ((int*)cnt)[tid + THREADS] = 0;

    // ---- prologue: cross-tile offsets + this chunk's absolute bases ----
    {
        int ct = 0, x = 0, gbt = 0;
        if (tid < NTILES) {
            gbt = gBaseT[(size_t)tid * NWA + chunk];    // within-tile base
            ct = gcnt[tid];
            x = ct;
#pragma unroll
            for (int s = 1; s < 64; s <<= 1) {
                int y = __shfl_up(x, s);
                if (lane >= s) x += y;
            }
            if (lane == 63) wsum[wl] = x;
        }
        __syncthreads();
        if (tid < NTILES) {
            int wpre = 0;
            for (int u = 0; u < wl; ++u) wpre += wsum[u];
            int off = wpre + x - ct;                // sum over tiles < tid
            gbase[tid] = off + gbt;
            if (b == 0) out_offsets[tid] = (float)off;
        }
    }
    __syncthreads();

    // ---- phase A: coalesced load + feature compute + ballot ranks ----
    unsigned int meta[2];
#pragma unroll
    for (int r2 = 0; r2 < 2; ++r2) {
        int o = wl * 128 + r2 * 64 + lane;          // monotone in global index
        int i = base_i + o;
        bool valid = i < N;
        int t = 0;
        if (valid) {
            float2 p  = pos2d[i];
            fv4 cv = __builtin_nontemporal_load((const fv4*)cov2d + i);  // stream, no-allocate
            float op  = opacity[i];
            t = tile_of(p.x, p.y);
            float a = cv[0], bb = cv[1], d = cv[3];
            float trace = a + d;
            float det = a * d - bb * bb;            // b == c (symmetric cov)
            float term1 = 0.5f * trace;
            float term2 = 0.5f * sqrtf(fmaxf(trace * trace - 4.0f * det, 0.0f));
            float rad = fmaxf(term1 - term2, term1 + term2);
            float inv = 1.0f / det;
            sFeat[0 * FSTRIDE + o] = p.x;
            sFeat[1 * FSTRIDE + o] = p.y;
            sFeat[2 * FSTRIDE + o] = d * inv;
            sFeat[3 * FSTRIDE + o] = -bb * inv;
            sFeat[4 * FSTRIDE + o] = a * inv;
            sFeat[5 * FSTRIDE + o] = op;
            sFeat[6 * FSTRIDE + o] = rad;
        }
        unsigned long long m = match_mask(t, valid);
        unsigned int pk = 0x80000000u;              // invalid marker
        if (valid) {
            unsigned long long below = m & ((1ull << lane) - 1ull);
            int rank = __popcll(below);
            int b0 = cnt[wl][t];                    // lockstep read-before-write
            if (below == 0ull) cnt[wl][t] = (unsigned short)(b0 + __popcll(m));
            pk = ((unsigned)t << 16) | (unsigned)(b0 + rank);
        }
        meta[r2] = pk;
    }
    __syncthreads();

    // ---- block scan over tiles (tid = tile) ----
    int tot = 0, x = 0;
    if (tid < NTILES) {
#pragma unroll
        for (int w = 0; w < NWAVES; ++w) tot += cnt[w][tid];
        x = tot;
#pragma unroll
        for (int s = 1; s < 64; s <<= 1) {
            int y = __shfl_up(x, s);
            if (lane >= s) x += y;
        }
        if (lane == 63) wsum[wl] = x;
    }
    __syncthreads();
    if (tid < NTILES) {
        int wpre = 0;
        for (int u = 0; u < wl; ++u) wpre += wsum[u];
        int run = wpre + x - tot;                   // tstart: block-local segment start
        int gb = gbase[tid];
        int ob = gb - run;
        obase[tid] = ob;
        base7[tid] = ob * 7;
#pragma unroll
        for (int w = 0; w < NWAVES; ++w) {          // per-wave bases, in place
            int cw = cnt[w][tid];
            cnt[w][tid] = (unsigned short)run;
            run += cw;
        }
    }
    __syncthreads();

    // ---- phase A2: write permutation plane ----
#pragma unroll
    for (int r2 = 0; r2 < 2; ++r2) {
        unsigned int pk = meta[r2];
        if (!(pk & 0x80000000u)) {
            int o = wl * 128 + r2 * 64 + lane;
            int t  = pk >> 16;
            int pw = pk & 0xFFFF;
            slotPk[cnt[wl][t] + pw] = ((unsigned)t << 16) | (unsigned)o;
        }
    }
    __syncthreads();

    // ---- phase B: float-linear coalesced write-out ----
    int nvalid = N - base_i; if (nvalid > CHUNK) nvalid = CHUNK;
    int nv7 = nvalid * 7;
    {
        int j = (int)((unsigned)tid / 7u);          // maintain j=f/7, c=f%7
        int c = tid - 7 * j;                        // (1024 = 146*7 + 2)
        for (int f = tid; f < nv7; f += THREADS) {
            unsigned int pk = slotPk[j];            // broadcast among 7 lanes sharing j
            int t = pk >> 16;
            int o = pk & 0xFFFF;
            out_feat[(size_t)(base7[t] + f)] = sFeat[c * FSTRIDE + o];
            j += 146; c += 2;
            if (c >= 7) { c -= 7; j += 1; }
        }
    }
    for (int j2 = tid; j2 < nvalid; j2 += THREADS) {
        unsigned int pk = slotPk[j2];
        out_order[obase[pk >> 16] + j2] = (float)(base_i + (int)(pk & 0xFFFF));
    }
}

extern "C" void kernel_launch(void* const* d_in, const int* in_sizes, int n_in,
                              void* d_out, int out_size, void* d_ws, size_t ws_size,
                              hipStream_t stream) {
    const float2* pos2d   = (const float2*)d_in[0];
    const float4* cov2d   = (const float4*)d_in[1];
    const float*  opacity = (const float*)d_in[2];
    const int N = in_sizes[2];           // opacity element count

    float* out         = (float*)d_out;  // layout: feat | counts | offsets | order
    float* out_feat    = out;
    float* out_counts  = out + (size_t)N * 7;
    float* out_offsets = out_counts + NTILES;
    float* out_order   = out_offsets + NTILES;

    int nchunks = (N + CHUNK - 1) / CHUNK;   // 977 for N=2M (k_scan supports <=2048)

    int* gTot   = (int*)d_ws;                          // [nchunks x NTILES]
    int* gBaseT = gTot + (size_t)nchunks * NTILES;     // [NTILES x nchunks]
    int* gcnt   = gBaseT + (size_t)NTILES * nchunks;   // [NTILES]

    k_hist<<<nchunks, THREADS, 0, stream>>>(pos2d, gTot, N);
    k_scan<<<NTILES, 512, 0, stream>>>(gTot, gBaseT, gcnt, out_counts, nchunks);
    k_scatter<<<nchunks, THREADS, 0, stream>>>(pos2d, cov2d, opacity, gBaseT, gcnt,
                                               out_feat, out_offsets, out_order,
                                               N, nchunks);
}